// Round 3
// baseline (1927.386 us; speedup 1.0000x reference)
//
#include <hip/hip_runtime.h>
#include <hip/hip_bf16.h>

typedef __hip_bfloat16 bf16;

__device__ __forceinline__ float b2f(bf16 v) { return __bfloat162float(v); }
__device__ __forceinline__ bf16  f2b(float v) { return __float2bfloat16(v); }

__device__ __forceinline__ float ldv(const bf16* p, int i)  { return b2f(p[i]); }
__device__ __forceinline__ float ldv(const float* p, int i) { return p[i]; }
__device__ __forceinline__ void  stv(bf16* p, size_t i, float v)  { p[i] = f2b(v); }
__device__ __forceinline__ void  stv(float* p, size_t i, float v) { p[i] = v; }

#define SELU_SCALE 1.0507009873554805f
#define SELU_ALPHA 1.6732632423543772f
#define INV_SQRT2  0.7071067811865475f

// dtype flag + global staging (B fixed at 2048 by the reference)
__device__ int   g_flag;                       // 1 = tensors are bf16, 0 = f32
__device__ float g_xx1[(size_t)2048 * 1860];   // conv-branch output
__device__ float g_xt [(size_t)2048 * 310];    // transformer output
__device__ float g_xcat[(size_t)2048 * 7936];  // GAT1 concat [62,128]

// ---- dtype probe: bf16 interpretation of real bf16 data is tame; of f32 data is wild
__global__ void k_probe(const void* x0)
{
    __shared__ int cnt;
    if (threadIdx.x == 0) cnt = 0;
    __syncthreads();
    const bf16* p = (const bf16*)x0;
    int bad = 0;
    for (int i = threadIdx.x; i < 4096; i += 256) {
        float v = b2f(p[i]);
        if (!(fabsf(v) < 1e6f)) bad++;     // catches NaN, Inf, wild exponents
    }
    atomicAdd(&cnt, bad);
    __syncthreads();
    if (threadIdx.x == 0) g_flag = (cnt < 32) ? 1 : 0;
}

// conv1d (torch VALID, stride 1) + bias + eval-BN + SELU; ends with barrier.
template<typename T>
__device__ void conv_bn_selu(int tid, const float* sIn, int Lin, int K, int Lout,
                             const T* __restrict__ W, const T* __restrict__ cb,
                             const T* __restrict__ bng, const T* __restrict__ bnb,
                             float* sOut, int ostride, int ooff)
{
    const float bninv = rsqrtf(1.0f + 1e-5f);
    for (int idx = tid; idx < 62 * Lout; idx += 256) {
        int o = idx / Lout, l = idx - o * Lout;
        const T* wr = W + o * 62 * K;
        float acc = 0.f;
        for (int i = 0; i < 62; ++i)
            for (int k = 0; k < K; ++k)
                acc += ldv(wr, i * K + k) * sIn[i * Lin + l + k];
        acc += ldv(cb, o);
        acc = acc * (ldv(bng, o) * bninv) + ldv(bnb, o);
        sOut[o * ostride + ooff + l] =
            (acc > 0.f) ? SELU_SCALE * acc : SELU_SCALE * SELU_ALPHA * expm1f(acc);
    }
    __syncthreads();
}

// ChannelAttention in-place on sIn [62,Ls]; opens and closes with barriers.
template<typename T>
__device__ void chan_att(int tid, float* sIn, int Ls,
                         const T* __restrict__ w1, const T* __restrict__ w2,
                         float* pool, float* hid)
{
    __syncthreads();
    if (tid < 124) {
        int which = tid >= 62; int n = which ? tid - 62 : tid;
        float a = 0.f, m = -3.4e38f;
        for (int l = 0; l < Ls; ++l) { float v = sIn[n * Ls + l]; a += v; m = fmaxf(m, v); }
        pool[tid] = which ? m : a / (float)Ls;
    }
    __syncthreads();
    if (tid < 30) {
        int which = tid / 15, j = tid - which * 15;
        const float* p = pool + which * 62;
        float acc = 0.f;
        for (int n = 0; n < 62; ++n) acc += p[n] * ldv(w1, j * 62 + n);
        hid[which * 16 + j] = fmaxf(acc, 0.f);
    }
    __syncthreads();
    if (tid < 62) {
        float acc = 0.f;
        for (int j = 0; j < 15; ++j) acc += (hid[j] + hid[16 + j]) * ldv(w2, tid * 15 + j);
        float g = 1.f / (1.f + expf(-acc));
        for (int l = 0; l < Ls; ++l) sIn[tid * Ls + l] *= g;
    }
    __syncthreads();
}

// GAT attention: att[n*62+m] = softmax_n( mask(0.8*L + 0.2*(s1[n]+s2[m])) )
template<typename T>
__device__ void gat_att(int tid, const T* __restrict__ A, const float* dinv,
                        const float* s1, const float* s2, float* att)
{
    __syncthreads();
    if (tid < 62) {
        int m = tid;
        float dm = dinv[m], sm = s2[m];
        float mx = -3.4e38f;
        for (int n = 0; n < 62; ++n) {
            float a = fmaxf(ldv(A, n * 62 + m), 0.f);
            float L = dinv[n] * a * dm;
            float dj = 0.8f * L + 0.2f * (s1[n] + sm);
            float v = dj > 0.f ? dj : -1e12f;
            att[n * 62 + m] = v; mx = fmaxf(mx, v);
        }
        float sum = 0.f;
        for (int n = 0; n < 62; ++n) { float e = expf(att[n * 62 + m] - mx); att[n * 62 + m] = e; sum += e; }
        float inv = 1.f / sum;
        for (int n = 0; n < 62; ++n) att[n * 62 + m] *= inv;
    }
    __syncthreads();
}

// ================= Kernel 1: conv branch -> g_xx1 =================
template<typename T, int MODE>
__global__ __launch_bounds__(256) void k_conv(
    const T* __restrict__ x,
    const T* __restrict__ cw3, const T* __restrict__ cb3,
    const T* __restrict__ cw5, const T* __restrict__ cb5,
    const T* __restrict__ bn_g, const T* __restrict__ bn_b,
    const T* __restrict__ ca_w1, const T* __restrict__ ca_w2)
{
    if (g_flag != MODE) return;
    __shared__ float sX[310], sx2[496], sbuf[868], sxx1[1860], spool[124], shid[32];
    const int tid = threadIdx.x;
    const int b = blockIdx.x;

    for (int i = tid; i < 310; i += 256) sX[i] = ldv(x, b * 310 + i);
    __syncthreads();

    // x1 [62,3] -> sx2 cols 0..2 (stride 8)
    conv_bn_selu(tid, sX, 5, 3, 3, cw3, cb3, bn_g, bn_b, sx2, 8, 0);
    for (int idx = tid; idx < 310; idx += 256) { int n = idx / 5, c = idx - n * 5; sx2[n * 8 + 3 + c] = sX[idx]; }
    chan_att(tid, sx2, 8, ca_w1, ca_w2, spool, shid);          // x2

    // x3 [62,6] -> sbuf(14) cols 8..13
    conv_bn_selu(tid, sx2, 8, 3, 6, cw3 + 11532, cb3 + 62, bn_g + 62, bn_b + 62, sbuf, 14, 8);
    for (int idx = tid; idx < 496; idx += 256) { int n = idx / 8, c = idx - n * 8; sbuf[n * 14 + c] = sx2[idx]; }
    __syncthreads();
    // x5 [62,12] -> sxx1 cols 0..11
    conv_bn_selu(tid, sbuf, 14, 3, 12, cw3 + 2 * 11532, cb3 + 124, bn_g + 124, bn_b + 124, sxx1, 30, 0);

    // x6 [62,4] -> sbuf(12) cols 0..3
    conv_bn_selu(tid, sx2, 8, 5, 4, cw5, cb5, bn_g + 186, bn_b + 186, sbuf, 12, 0);
    for (int idx = tid; idx < 496; idx += 256) { int n = idx / 8, c = idx - n * 8; sbuf[n * 12 + 4 + c] = sx2[idx]; }
    __syncthreads();
    // x8 [62,8] -> sxx1 cols 12..19
    conv_bn_selu(tid, sbuf, 12, 5, 8, cw5 + 19220, cb5 + 62, bn_g + 248, bn_b + 248, sxx1, 30, 12);

    // x9 [62,6] -> sbuf(14) cols 0..5
    conv_bn_selu(tid, sx2, 8, 3, 6, cw3 + 3 * 11532, cb3 + 186, bn_g + 310, bn_b + 310, sbuf, 14, 0);
    for (int idx = tid; idx < 496; idx += 256) { int n = idx / 8, c = idx - n * 8; sbuf[n * 14 + 6 + c] = sx2[idx]; }
    __syncthreads();
    // x11c [62,10] -> sxx1 cols 20..29
    conv_bn_selu(tid, sbuf, 14, 5, 10, cw5 + 2 * 19220, cb5 + 124, bn_g + 372, bn_b + 372, sxx1, 30, 20);

    chan_att(tid, sxx1, 30, ca_w1 + 930, ca_w2 + 930, spool, shid);   // xx1

    for (int i = tid; i < 1860; i += 256) g_xx1[(size_t)b * 1860 + i] = sxx1[i];
}

// ================= Kernel 2: transformer -> g_xt =================
template<typename T, int MODE>
__global__ __launch_bounds__(256) void k_trans(
    const T* __restrict__ x,
    const T* __restrict__ qw, const T* __restrict__ qb,
    const T* __restrict__ kw, const T* __restrict__ kb,
    const T* __restrict__ vw, const T* __restrict__ vb,
    const T* __restrict__ lin1_w, const T* __restrict__ lin1_b,
    const T* __restrict__ ln1_g, const T* __restrict__ ln1_b,
    const T* __restrict__ ln2_g, const T* __restrict__ ln2_b,
    const T* __restrict__ ffn_w1, const T* __restrict__ ffn_b1,
    const T* __restrict__ ffn_w2, const T* __restrict__ ffn_b2)
{
    if (g_flag != MODE) return;
    __shared__ float sX[310], sxf[310], sq[744], sk[744], sv[1860];
    __shared__ float satt[3844], sx2t[1860], sx21[310], shg[186];
    const int tid = threadIdx.x;
    const int b = blockIdx.x;

    for (int i = tid; i < 310; i += 256) sX[i] = ldv(x, b * 310 + i);
    __syncthreads();

    if (tid < 62) {   // LN1 over last dim (5)
        float m = 0.f, s = 0.f;
        for (int c = 0; c < 5; ++c) { float v = sX[tid * 5 + c]; m += v; s += v * v; }
        m *= 0.2f;
        float inv = rsqrtf(fmaxf(s * 0.2f - m * m, 0.f) + 1e-5f);
        for (int c = 0; c < 5; ++c)
            sxf[tid * 5 + c] = (sX[tid * 5 + c] - m) * inv * ldv(ln1_g, c) + ldv(ln1_b, c);
    }
    __syncthreads();

    for (int idx = tid; idx < 744; idx += 256) {      // Q [6,124]
        int h = idx / 124, o = idx - h * 124;
        float acc = 0.f;
        for (int f = 0; f < 310; ++f) acc += sxf[f] * ldv(qw, h * 38440 + f * 124 + o);
        sq[idx] = acc + ldv(qb, idx);
    }
    for (int idx = tid; idx < 744; idx += 256) {      // K [6,124]
        int h = idx / 124, o = idx - h * 124;
        float acc = 0.f;
        for (int f = 0; f < 310; ++f) acc += sxf[f] * ldv(kw, h * 38440 + f * 124 + o);
        sk[idx] = acc + ldv(kb, idx);
    }
    for (int idx = tid; idx < 1860; idx += 256) {     // V [6,310]
        int h = idx / 310, o = idx - h * 310;
        float acc = 0.f;
        for (int f = 0; f < 310; ++f) acc += sxf[f] * ldv(vw, h * 96100 + f * 310 + o);
        sv[idx] = acc + ldv(vb, idx);
    }
    __syncthreads();

    for (int h = 0; h < 6; ++h) {
        const float* q = sq + h * 124;
        const float* k = sk + h * 124;
        for (int idx = tid; idx < 3844; idx += 256) {
            int i = idx / 62, j = idx - i * 62;
            satt[idx] = (q[i * 2] * k[j * 2] + q[i * 2 + 1] * k[j * 2 + 1]) * INV_SQRT2;
        }
        __syncthreads();
        if (tid < 62) {          // softmax over j
            float* row = satt + tid * 62;
            float mx = -3.4e38f;
            for (int j = 0; j < 62; ++j) mx = fmaxf(mx, row[j]);
            float sum = 0.f;
            for (int j = 0; j < 62; ++j) { float e = expf(row[j] - mx); row[j] = e; sum += e; }
            float inv = 1.f / sum;
            for (int j = 0; j < 62; ++j) row[j] *= inv;
        }
        __syncthreads();
        const float* v = sv + h * 310;
        for (int idx = tid; idx < 310; idx += 256) {   // o[i,c] = sum_j attn[j,i] v[j,c]
            int i = idx / 5, c = idx - i * 5;
            float acc = 0.f;
            for (int j = 0; j < 62; ++j) acc += satt[j * 62 + i] * v[j * 5 + c];
            sx2t[i * 30 + h * 5 + c] = acc;
        }
        __syncthreads();
    }

    for (int o = tid; o < 310; o += 256) {    // lin1 + residual x
        float acc = ldv(lin1_b, o);
        for (int f = 0; f < 1860; ++f) acc += sx2t[f] * ldv(lin1_w, f * 310 + o);
        sx21[o] = acc + sX[o];
    }
    __syncthreads();

    if (tid < 62) {   // LN2 -> sxf
        float m = 0.f, s = 0.f;
        for (int c = 0; c < 5; ++c) { float v = sx21[tid * 5 + c]; m += v; s += v * v; }
        m *= 0.2f;
        float inv = rsqrtf(fmaxf(s * 0.2f - m * m, 0.f) + 1e-5f);
        for (int c = 0; c < 5; ++c)
            sxf[tid * 5 + c] = (sx21[tid * 5 + c] - m) * inv * ldv(ln2_g, c) + ldv(ln2_b, c);
    }
    __syncthreads();

    for (int j = tid; j < 186; j += 256) {    // FFN up + exact gelu
        float acc = ldv(ffn_b1, j);
        for (int f = 0; f < 310; ++f) acc += sxf[f] * ldv(ffn_w1, f * 186 + j);
        shg[j] = 0.5f * acc * (1.f + erff(acc * INV_SQRT2));
    }
    __syncthreads();
    for (int o = tid; o < 310; o += 256) {    // FFN down + residual
        float acc = ldv(ffn_b2, o);
        for (int j = 0; j < 186; ++j) acc += shg[j] * ldv(ffn_w2, j * 310 + o);
        g_xt[(size_t)b * 310 + o] = acc + sx21[o];
    }
}

// ================= Kernel 3: GAT x2 + log_softmax + fc head =================
template<typename T, int MODE>
__global__ __launch_bounds__(256) void k_gat(
    const T* __restrict__ A,
    const T* __restrict__ gat_w, const T* __restrict__ gat_a,
    const T* __restrict__ out_w, const T* __restrict__ out_a,
    const T* __restrict__ fc1_w, const T* __restrict__ fc1_b,
    const T* __restrict__ fc2_w, const T* __restrict__ fc2_b,
    const T* __restrict__ fc3_w, const T* __restrict__ fc3_b,
    T* __restrict__ out, int B)
{
    if (g_flag != MODE) return;
    __shared__ float sxx[2170], satt[3844], sh[1984];
    __shared__ float sdinv[62], ss1[62], ss2[62];
    __shared__ float sh2[620], soutg[620], sx11[620], st1[256], st2[32];
    const int tid = threadIdx.x;
    const int b = blockIdx.x;
    float* xcat = g_xcat + (size_t)b * 7936;

    for (int idx = tid; idx < 2170; idx += 256) {
        int n = idx / 35, f = idx - n * 35;
        sxx[idx] = (f < 30) ? g_xx1[(size_t)b * 1860 + n * 30 + f]
                            : g_xt[(size_t)b * 310 + n * 5 + (f - 30)];
    }
    if (tid < 62) {
        float s = 0.f;
        for (int m = 0; m < 62; ++m) s += fmaxf(ldv(A, tid * 62 + m), 0.f);
        sdinv[tid] = rsqrtf(s + 1e-10f);
    }
    __syncthreads();

    // GAT layer 1: 4 heads, Fin=35, Fo=32
    for (int h = 0; h < 4; ++h) {
        for (int idx = tid; idx < 1984; idx += 256) {
            int n = idx / 32, o = idx - n * 32;
            float acc = 0.f;
            for (int f = 0; f < 35; ++f) acc += sxx[n * 35 + f] * ldv(gat_w, h * 1120 + f * 32 + o);
            sh[idx] = acc;
        }
        __syncthreads();
        if (tid < 124) {
            int which = tid >= 62; int n = which ? tid - 62 : tid;
            float acc = 0.f;
            for (int o = 0; o < 32; ++o) {
                float v = sh[n * 32 + o]; v = v > 0.f ? v : 0.2f * v;   // leaky_relu(0.2)
                acc += v * ldv(gat_a, h * 64 + which * 32 + o);
            }
            (which ? ss2 : ss1)[n] = acc;
        }
        gat_att(tid, A, sdinv, ss1, ss2, satt);
        for (int idx = tid; idx < 1984; idx += 256) {
            int i = idx / 32, o = idx - i * 32;
            float acc = 0.f;
            for (int j = 0; j < 62; ++j) acc += satt[i * 62 + j] * sh[j * 32 + o];
            xcat[i * 128 + h * 32 + o] = fmaxf(acc, 0.f);
        }
        __syncthreads();
    }

    // GAT layer 2: Fin=128, Fo=10
    for (int idx = tid; idx < 620; idx += 256) {
        int n = idx / 10, o = idx - n * 10;
        float acc = 0.f;
        for (int f = 0; f < 128; ++f) acc += xcat[n * 128 + f] * ldv(out_w, f * 10 + o);
        sh2[idx] = acc;
    }
    __syncthreads();
    if (tid < 124) {
        int which = tid >= 62; int n = which ? tid - 62 : tid;
        float acc = 0.f;
        for (int o = 0; o < 10; ++o) {
            float v = sh2[n * 10 + o]; v = v > 0.f ? v : 0.2f * v;
            acc += v * ldv(out_a, which * 10 + o);
        }
        (which ? ss2 : ss1)[n] = acc;
    }
    gat_att(tid, A, sdinv, ss1, ss2, satt);
    for (int idx = tid; idx < 620; idx += 256) {
        int i = idx / 10, o = idx - i * 10;
        float acc = 0.f;
        for (int j = 0; j < 62; ++j) acc += satt[i * 62 + j] * sh2[j * 10 + o];
        soutg[idx] = fmaxf(acc, 0.f);
    }
    __syncthreads();

    if (tid < 62) {   // g1 = log_softmax(elu(outg)) -> x11 (first output)
        const float* r = soutg + tid * 10;
        float e[10]; float mx = -3.4e38f;
        for (int o = 0; o < 10; ++o) { float v = r[o]; v = v > 0.f ? v : expm1f(v); e[o] = v; mx = fmaxf(mx, v); }
        float sum = 0.f;
        for (int o = 0; o < 10; ++o) sum += expf(e[o] - mx);
        float ls = logf(sum) + mx;
        for (int o = 0; o < 10; ++o) {
            float v = e[o] - ls;
            sx11[tid * 10 + o] = v;
            stv(out, (size_t)b * 620 + tid * 10 + o, v);
        }
    }
    __syncthreads();

    {   // fc1 (620->256)
        float acc = ldv(fc1_b, tid);
        for (int f = 0; f < 620; ++f) acc += sx11[f] * ldv(fc1_w, f * 256 + tid);
        st1[tid] = acc;
    }
    __syncthreads();
    if (tid < 32) {   // fc2 (256->32)
        float acc = ldv(fc2_b, tid);
        for (int f = 0; f < 256; ++f) acc += st1[f] * ldv(fc2_w, f * 32 + tid);
        st2[tid] = acc;
    }
    __syncthreads();
    if (tid < 4) {    // fc3 (32->4) -> x4 (second output)
        float acc = ldv(fc3_b, tid);
        for (int f = 0; f < 32; ++f) acc += st2[f] * ldv(fc3_w, f * 4 + tid);
        stv(out, (size_t)B * 620 + b * 4 + tid, acc);
    }
}

extern "C" void kernel_launch(void* const* d_in, const int* in_sizes, int n_in,
                              void* d_out, int out_size, void* d_ws, size_t ws_size,
                              hipStream_t stream)
{
    const int B = in_sizes[0] / 310;   // 2048

    k_probe<<<1, 256, 0, stream>>>(d_in[0]);

    // ---- bf16 instantiation (MODE 1) ----
    {
        #define P(i) ((const bf16*)d_in[i])
        k_conv<bf16,1><<<B, 256, 0, stream>>>(P(0), P(2), P(3), P(4), P(5), P(6), P(7), P(8), P(9));
        k_trans<bf16,1><<<B, 256, 0, stream>>>(P(0), P(10), P(11), P(12), P(13), P(14), P(15),
                                               P(16), P(17), P(18), P(19), P(20), P(21),
                                               P(22), P(23), P(24), P(25));
        k_gat<bf16,1><<<B, 256, 0, stream>>>(P(1), P(26), P(27), P(28), P(29), P(30), P(31),
                                             P(32), P(33), P(34), P(35), (bf16*)d_out, B);
        #undef P
    }
    // ---- f32 instantiation (MODE 0) ----
    {
        #define P(i) ((const float*)d_in[i])
        k_conv<float,0><<<B, 256, 0, stream>>>(P(0), P(2), P(3), P(4), P(5), P(6), P(7), P(8), P(9));
        k_trans<float,0><<<B, 256, 0, stream>>>(P(0), P(10), P(11), P(12), P(13), P(14), P(15),
                                                P(16), P(17), P(18), P(19), P(20), P(21),
                                                P(22), P(23), P(24), P(25));
        k_gat<float,0><<<B, 256, 0, stream>>>(P(1), P(26), P(27), P(28), P(29), P(30), P(31),
                                              P(32), P(33), P(34), P(35), (float*)d_out, B);
        #undef P
    }
}

// Round 4
// 1263.332 us; speedup vs baseline: 1.5256x; 1.5256x over previous
//
#include <hip/hip_runtime.h>
#include <hip/hip_bf16.h>

typedef __hip_bfloat16 bf16;

__device__ __forceinline__ float b2f(bf16 v) { return __bfloat162float(v); }
__device__ __forceinline__ bf16  f2b(float v) { return __float2bfloat16(v); }

__device__ __forceinline__ float ldv(const bf16* p, int i)  { return b2f(p[i]); }
__device__ __forceinline__ float ldv(const float* p, int i) { return p[i]; }
__device__ __forceinline__ void  stv(bf16* p, size_t i, float v)  { p[i] = f2b(v); }
__device__ __forceinline__ void  stv(float* p, size_t i, float v) { p[i] = v; }

#define SELU_SCALE 1.0507009873554805f
#define SELU_ALPHA 1.6732632423543772f
#define INV_SQRT2  0.7071067811865475f

#define NB 2048   // batch (fixed by reference)

// dtype flag + global staging
__device__ int   g_flag;                        // 1 = bf16 tensors, 0 = f32
__device__ float g_xf  [(size_t)NB * 310];      // ln1(x)
__device__ float g_qkv [(size_t)NB * 3348];     // q(744)|k(744)|v(1860) per sample
__device__ float g_x2t [(size_t)NB * 1860];     // attention output (pre-lin1)
__device__ float g_xx1 [(size_t)NB * 1860];     // conv-branch output
__device__ float g_xt  [(size_t)NB * 310];      // transformer output
__device__ float g_xcat[(size_t)NB * 7936];     // GAT1 concat [62,128]
__device__ float g_L   [3844];                  // normalized Laplacian
// ---- dtype probe ----
__global__ void k_probe(const void* x0)
{
    __shared__ int cnt;
    if (threadIdx.x == 0) cnt = 0;
    __syncthreads();
    const bf16* p = (const bf16*)x0;
    int bad = 0;
    for (int i = threadIdx.x; i < 4096; i += 256) {
        float v = b2f(p[i]);
        if (!(fabsf(v) < 1e6f)) bad++;
    }
    atomicAdd(&cnt, bad);
    __syncthreads();
    if (threadIdx.x == 0) g_flag = (cnt < 32) ? 1 : 0;
}

// ================= conv branch, G=4 samples/block =================
// All LDS activation arrays are [pos][g] with g fastest (float4-friendly).
template<typename T>
__device__ void conv_bn_selu_g(int tid, const float* sIn, int Lin, int K, int Lout,
                               const T* __restrict__ W, const T* __restrict__ cb,
                               const T* __restrict__ bng, const T* __restrict__ bnb,
                               float* sOut, int ostride, int ooff)
{
    const float bninv = rsqrtf(1.0f + 1e-5f);
    for (int idx = tid; idx < 62 * Lout; idx += 256) {
        int o = idx / Lout, l = idx - o * Lout;
        const T* wr = W + o * 62 * K;
        float a0 = 0.f, a1 = 0.f, a2 = 0.f, a3 = 0.f;
        for (int i = 0; i < 62; ++i)
            for (int k = 0; k < K; ++k) {
                float w = ldv(wr, i * K + k);
                const float4 xv = *(const float4*)(sIn + (i * Lin + l + k) * 4);
                a0 += w * xv.x; a1 += w * xv.y; a2 += w * xv.z; a3 += w * xv.w;
            }
        float bias = ldv(cb, o), gg = ldv(bng, o) * bninv, bb = ldv(bnb, o);
        float acc[4] = {a0, a1, a2, a3};
        for (int g = 0; g < 4; ++g) {
            float v = (acc[g] + bias) * gg + bb;
            sOut[(o * ostride + ooff + l) * 4 + g] =
                (v > 0.f) ? SELU_SCALE * v : SELU_SCALE * SELU_ALPHA * expm1f(v);
        }
    }
    __syncthreads();
}

template<typename T>
__device__ void chan_att_g(int tid, float* sIn, int Ls,
                           const T* __restrict__ w1, const T* __restrict__ w2,
                           float* pool, float* hid)   // pool[124*4], hid[32*4]
{
    __syncthreads();
    for (int idx = tid; idx < 496; idx += 256) {
        int which = idx >= 248; int r = idx - which * 248;
        int n = r >> 2, g = r & 3;
        float a = 0.f, m = -3.4e38f;
        for (int l = 0; l < Ls; ++l) { float v = sIn[(n * Ls + l) * 4 + g]; a += v; m = fmaxf(m, v); }
        pool[(which * 62 + n) * 4 + g] = which ? m : a / (float)Ls;
    }
    __syncthreads();
    if (tid < 120) {
        int g = tid & 3; int t = tid >> 2;         // t in [0,30)
        int which = t / 15, j = t - which * 15;
        float acc = 0.f;
        for (int n = 0; n < 62; ++n) acc += pool[(which * 62 + n) * 4 + g] * ldv(w1, j * 62 + n);
        hid[(which * 16 + j) * 4 + g] = fmaxf(acc, 0.f);
    }
    __syncthreads();
    if (tid < 248) {
        int g = tid & 3, n = tid >> 2;
        float acc = 0.f;
        for (int j = 0; j < 15; ++j) acc += (hid[j * 4 + g] + hid[(16 + j) * 4 + g]) * ldv(w2, n * 15 + j);
        float s = 1.f / (1.f + expf(-acc));
        for (int l = 0; l < Ls; ++l) sIn[(n * Ls + l) * 4 + g] *= s;
    }
    __syncthreads();
}

template<typename T, int MODE>
__global__ __launch_bounds__(256) void k_conv(
    const T* __restrict__ x,
    const T* __restrict__ cw3, const T* __restrict__ cb3,
    const T* __restrict__ cw5, const T* __restrict__ cb5,
    const T* __restrict__ bn_g, const T* __restrict__ bn_b,
    const T* __restrict__ ca_w1, const T* __restrict__ ca_w2)
{
    if (g_flag != MODE) return;
    __shared__ __align__(16) float sX[310 * 4];
    __shared__ __align__(16) float sx2[496 * 4];
    __shared__ __align__(16) float sbuf[868 * 4];
    __shared__ __align__(16) float sxx1[1860 * 4];
    __shared__ float spool[124 * 4], shid[32 * 4];
    const int tid = threadIdx.x;
    const int grp = blockIdx.x;          // 4 samples per block

    for (int idx = tid; idx < 310 * 4; idx += 256) {
        int o = idx >> 2, g = idx & 3;
        sX[idx] = ldv(x, (grp * 4 + g) * 310 + o);
    }
    __syncthreads();

    // x1 [62,3] -> sx2 cols 0..2 (stride 8)
    conv_bn_selu_g(tid, sX, 5, 3, 3, cw3, cb3, bn_g, bn_b, sx2, 8, 0);
    for (int idx = tid; idx < 310 * 4; idx += 256) {
        int p = idx >> 2, g = idx & 3; int n = p / 5, c = p - n * 5;
        sx2[(n * 8 + 3 + c) * 4 + g] = sX[idx];
    }
    chan_att_g(tid, sx2, 8, ca_w1, ca_w2, spool, shid);          // x2

    // x3 [62,6] -> sbuf(14) cols 8..13
    conv_bn_selu_g(tid, sx2, 8, 3, 6, cw3 + 11532, cb3 + 62, bn_g + 62, bn_b + 62, sbuf, 14, 8);
    for (int idx = tid; idx < 496 * 4; idx += 256) {
        int p = idx >> 2, g = idx & 3; int n = p >> 3, c = p & 7;
        sbuf[(n * 14 + c) * 4 + g] = sx2[idx];
    }
    __syncthreads();
    // x5 [62,12] -> sxx1 cols 0..11
    conv_bn_selu_g(tid, sbuf, 14, 3, 12, cw3 + 2 * 11532, cb3 + 124, bn_g + 124, bn_b + 124, sxx1, 30, 0);

    // x6 [62,4] -> sbuf(12) cols 0..3
    conv_bn_selu_g(tid, sx2, 8, 5, 4, cw5, cb5, bn_g + 186, bn_b + 186, sbuf, 12, 0);
    for (int idx = tid; idx < 496 * 4; idx += 256) {
        int p = idx >> 2, g = idx & 3; int n = p >> 3, c = p & 7;
        sbuf[(n * 12 + 4 + c) * 4 + g] = sx2[idx];
    }
    __syncthreads();
    // x8 [62,8] -> sxx1 cols 12..19
    conv_bn_selu_g(tid, sbuf, 12, 5, 8, cw5 + 19220, cb5 + 62, bn_g + 248, bn_b + 248, sxx1, 30, 12);

    // x9 [62,6] -> sbuf(14) cols 0..5
    conv_bn_selu_g(tid, sx2, 8, 3, 6, cw3 + 3 * 11532, cb3 + 186, bn_g + 310, bn_b + 310, sbuf, 14, 0);
    for (int idx = tid; idx < 496 * 4; idx += 256) {
        int p = idx >> 2, g = idx & 3; int n = p >> 3, c = p & 7;
        sbuf[(n * 14 + 6 + c) * 4 + g] = sx2[idx];
    }
    __syncthreads();
    // x11c [62,10] -> sxx1 cols 20..29
    conv_bn_selu_g(tid, sbuf, 14, 5, 10, cw5 + 2 * 19220, cb5 + 124, bn_g + 372, bn_b + 372, sxx1, 30, 20);

    chan_att_g(tid, sxx1, 30, ca_w1 + 930, ca_w2 + 930, spool, shid);   // xx1

    for (int idx = tid; idx < 1860 * 4; idx += 256) {
        int p = idx >> 2, g = idx & 3;
        g_xx1[(size_t)(grp * 4 + g) * 1860 + p] = sxx1[idx];
    }
}

// ================= transformer =================
// LN1 rows: one thread per (b,i)
template<typename T, int MODE>
__global__ __launch_bounds__(256) void k_ln1(
    const T* __restrict__ x, const T* __restrict__ ln1_g, const T* __restrict__ ln1_b, int B)
{
    if (g_flag != MODE) return;
    int r = blockIdx.x * 256 + threadIdx.x;
    if (r >= B * 62) return;
    int b = r / 62, i = r - b * 62;
    float xv[5], m = 0.f, s = 0.f;
    for (int c = 0; c < 5; ++c) { xv[c] = ldv(x, b * 310 + i * 5 + c); m += xv[c]; s += xv[c] * xv[c]; }
    m *= 0.2f;
    float inv = rsqrtf(fmaxf(s * 0.2f - m * m, 0.f) + 1e-5f);
    for (int c = 0; c < 5; ++c)
        g_xf[(size_t)b * 310 + i * 5 + c] = (xv[c] - m) * inv * ldv(ln1_g, c) + ldv(ln1_b, c);
}

// QKV projection GEMM: 8 samples/block, 256 outputs/block tile; 14 tiles cover 3348.
template<typename T, int MODE>
__global__ __launch_bounds__(256) void k_qkv(
    const T* __restrict__ qw, const T* __restrict__ qb,
    const T* __restrict__ kw, const T* __restrict__ kb,
    const T* __restrict__ vw, const T* __restrict__ vb)
{
    if (g_flag != MODE) return;
    __shared__ __align__(16) float sxf[310 * 8];
    const int tid = threadIdx.x;
    const int grp = blockIdx.x / 14;
    const int tile = blockIdx.x - grp * 14;

    for (int idx = tid; idx < 310 * 8; idx += 256) {
        int f = idx >> 3, g = idx & 7;
        sxf[idx] = g_xf[(size_t)(grp * 8 + g) * 310 + f];
    }
    __syncthreads();

    int o = tile * 256 + tid;
    if (o >= 3348) return;

    const T* W; int stride; float bias;
    if (o < 744)       { int h = o / 124, c = o - h * 124; W = qw + h * 38440 + c; stride = 124; bias = ldv(qb, o); }
    else if (o < 1488) { int r = o - 744;  int h = r / 124, c = r - h * 124; W = kw + h * 38440 + c; stride = 124; bias = ldv(kb, r); }
    else               { int r = o - 1488; int h = r / 310, c = r - h * 310; W = vw + h * 96100 + c; stride = 310; bias = ldv(vb, r); }

    float a0 = bias, a1 = bias, a2 = bias, a3 = bias, a4 = bias, a5 = bias, a6 = bias, a7 = bias;
    for (int f = 0; f < 310; ++f) {
        float w = ldv(W, f * stride);
        const float4 p = *(const float4*)(sxf + f * 8);
        const float4 q = *(const float4*)(sxf + f * 8 + 4);
        a0 += w * p.x; a1 += w * p.y; a2 += w * p.z; a3 += w * p.w;
        a4 += w * q.x; a5 += w * q.y; a6 += w * q.z; a7 += w * q.w;
    }
    float acc[8] = {a0, a1, a2, a3, a4, a5, a6, a7};
    for (int g = 0; g < 8; ++g) g_qkv[(size_t)(grp * 8 + g) * 3348 + o] = acc[g];
}

// per-sample attention -> g_x2t (dtype-free; launched once)
__global__ __launch_bounds__(256) void k_attn()
{
    __shared__ float sqkv[3348];
    __shared__ float satt[3844];
    const int tid = threadIdx.x;
    const int b = blockIdx.x;

    for (int i = tid; i < 3348; i += 256) sqkv[i] = g_qkv[(size_t)b * 3348 + i];
    __syncthreads();

    for (int h = 0; h < 6; ++h) {
        const float* q = sqkv + h * 124;
        const float* k = sqkv + 744 + h * 124;
        const float* v = sqkv + 1488 + h * 310;
        for (int idx = tid; idx < 3844; idx += 256) {
            int i = idx / 62, j = idx - i * 62;
            satt[idx] = (q[i * 2] * k[j * 2] + q[i * 2 + 1] * k[j * 2 + 1]) * INV_SQRT2;
        }
        __syncthreads();
        if (tid < 62) {          // softmax over j
            float* row = satt + tid * 62;
            float mx = -3.4e38f;
            for (int j = 0; j < 62; ++j) mx = fmaxf(mx, row[j]);
            float sum = 0.f;
            for (int j = 0; j < 62; ++j) { float e = expf(row[j] - mx); row[j] = e; sum += e; }
            float inv = 1.f / sum;
            for (int j = 0; j < 62; ++j) row[j] *= inv;
        }
        __syncthreads();
        for (int idx = tid; idx < 310; idx += 256) {   // o[i,c] = sum_j attn[j,i] v[j,c]
            int i = idx / 5, c = idx - i * 5;
            float acc = 0.f;
            for (int j = 0; j < 62; ++j) acc += satt[j * 62 + i] * v[j * 5 + c];
            g_x2t[(size_t)b * 1860 + i * 30 + h * 5 + c] = acc;
        }
        __syncthreads();
    }
}

// lin1 + residual + LN2 + FFN + residual: 4 samples/block
template<typename T, int MODE>
__global__ __launch_bounds__(256) void k_lin1ffn(
    const T* __restrict__ x,
    const T* __restrict__ lin1_w, const T* __restrict__ lin1_b,
    const T* __restrict__ ln2_g, const T* __restrict__ ln2_b,
    const T* __restrict__ ffn_w1, const T* __restrict__ ffn_b1,
    const T* __restrict__ ffn_w2, const T* __restrict__ ffn_b2)
{
    if (g_flag != MODE) return;
    __shared__ __align__(16) float sx2t[1860 * 4];
    __shared__ __align__(16) float sX[310 * 4];
    __shared__ __align__(16) float sx21[310 * 4];
    __shared__ __align__(16) float sxf[310 * 4];
    __shared__ __align__(16) float shg[186 * 4];
    const int tid = threadIdx.x;
    const int grp = blockIdx.x;

    for (int idx = tid; idx < 1860 * 4; idx += 256) {
        int f = idx >> 2, g = idx & 3;
        sx2t[idx] = g_x2t[(size_t)(grp * 4 + g) * 1860 + f];
    }
    for (int idx = tid; idx < 310 * 4; idx += 256) {
        int o = idx >> 2, g = idx & 3;
        sX[idx] = ldv(x, (grp * 4 + g) * 310 + o);
    }
    __syncthreads();

    // lin1 + residual
    for (int o = tid; o < 310; o += 256) {
        float bias = ldv(lin1_b, o);
        float a0 = bias, a1 = bias, a2 = bias, a3 = bias;
        for (int f = 0; f < 1860; ++f) {
            float w = ldv(lin1_w, f * 310 + o);
            const float4 xv = *(const float4*)(sx2t + f * 4);
            a0 += w * xv.x; a1 += w * xv.y; a2 += w * xv.z; a3 += w * xv.w;
        }
        sx21[o * 4 + 0] = a0 + sX[o * 4 + 0];
        sx21[o * 4 + 1] = a1 + sX[o * 4 + 1];
        sx21[o * 4 + 2] = a2 + sX[o * 4 + 2];
        sx21[o * 4 + 3] = a3 + sX[o * 4 + 3];
    }
    __syncthreads();

    // LN2
    if (tid < 248) {
        int i = tid >> 2, g = tid & 3;
        float m = 0.f, s = 0.f;
        for (int c = 0; c < 5; ++c) { float v = sx21[(i * 5 + c) * 4 + g]; m += v; s += v * v; }
        m *= 0.2f;
        float inv = rsqrtf(fmaxf(s * 0.2f - m * m, 0.f) + 1e-5f);
        for (int c = 0; c < 5; ++c)
            sxf[(i * 5 + c) * 4 + g] = (sx21[(i * 5 + c) * 4 + g] - m) * inv * ldv(ln2_g, c) + ldv(ln2_b, c);
    }
    __syncthreads();

    // FFN up + exact gelu
    if (tid < 186) {
        int j = tid;
        float bias = ldv(ffn_b1, j);
        float a0 = bias, a1 = bias, a2 = bias, a3 = bias;
        for (int f = 0; f < 310; ++f) {
            float w = ldv(ffn_w1, f * 186 + j);
            const float4 xv = *(const float4*)(sxf + f * 4);
            a0 += w * xv.x; a1 += w * xv.y; a2 += w * xv.z; a3 += w * xv.w;
        }
        shg[j * 4 + 0] = 0.5f * a0 * (1.f + erff(a0 * INV_SQRT2));
        shg[j * 4 + 1] = 0.5f * a1 * (1.f + erff(a1 * INV_SQRT2));
        shg[j * 4 + 2] = 0.5f * a2 * (1.f + erff(a2 * INV_SQRT2));
        shg[j * 4 + 3] = 0.5f * a3 * (1.f + erff(a3 * INV_SQRT2));
    }
    __syncthreads();

    // FFN down + residual -> g_xt
    for (int o = tid; o < 310; o += 256) {
        float bias = ldv(ffn_b2, o);
        float a0 = bias, a1 = bias, a2 = bias, a3 = bias;
        for (int j = 0; j < 186; ++j) {
            float w = ldv(ffn_w2, j * 310 + o);
            const float4 xv = *(const float4*)(shg + j * 4);
            a0 += w * xv.x; a1 += w * xv.y; a2 += w * xv.z; a3 += w * xv.w;
        }
        g_xt[(size_t)(grp * 4 + 0) * 310 + o] = a0 + sx21[o * 4 + 0];
        g_xt[(size_t)(grp * 4 + 1) * 310 + o] = a1 + sx21[o * 4 + 1];
        g_xt[(size_t)(grp * 4 + 2) * 310 + o] = a2 + sx21[o * 4 + 2];
        g_xt[(size_t)(grp * 4 + 3) * 310 + o] = a3 + sx21[o * 4 + 3];
    }
}

// ================= GAT =================
// normalized Laplacian prep (1 block)
template<typename T, int MODE>
__global__ __launch_bounds__(256) void k_prep(const T* __restrict__ A)
{
    if (g_flag != MODE) return;
    __shared__ float sdinv[62];
    const int tid = threadIdx.x;
    if (tid < 62) {
        float s = 0.f;
        for (int m = 0; m < 62; ++m) s += fmaxf(ldv(A, tid * 62 + m), 0.f);
        sdinv[tid] = rsqrtf(s + 1e-10f);
    }
    __syncthreads();
    for (int idx = tid; idx < 3844; idx += 256) {
        int n = idx / 62, m = idx - n * 62;
        g_L[idx] = sdinv[n] * fmaxf(ldv(A, idx), 0.f) * sdinv[m];
    }
}

// GAT attention from staged L: softmax over n per column m.
__device__ void gat_att_L(int tid, const float* sL, const float* s1, const float* s2, float* att)
{
    __syncthreads();
    if (tid < 62) {
        int m = tid;
        float sm = s2[m];
        float mx = -3.4e38f;
        for (int n = 0; n < 62; ++n) {
            float dj = 0.8f * sL[n * 62 + m] + 0.2f * (s1[n] + sm);
            float v = dj > 0.f ? dj : -1e12f;
            att[n * 62 + m] = v; mx = fmaxf(mx, v);
        }
        float sum = 0.f;
        for (int n = 0; n < 62; ++n) { float e = expf(att[n * 62 + m] - mx); att[n * 62 + m] = e; sum += e; }
        float inv = 1.f / sum;
        for (int n = 0; n < 62; ++n) att[n * 62 + m] *= inv;
    }
    __syncthreads();
}

template<typename T, int MODE>
__global__ __launch_bounds__(256) void k_gat(
    const T* __restrict__ gat_w, const T* __restrict__ gat_a,
    const T* __restrict__ out_w, const T* __restrict__ out_a,
    const T* __restrict__ fc1_w, const T* __restrict__ fc1_b,
    const T* __restrict__ fc2_w, const T* __restrict__ fc2_b,
    const T* __restrict__ fc3_w, const T* __restrict__ fc3_b,
    T* __restrict__ out, int B)
{
    if (g_flag != MODE) return;
    __shared__ float sxx[2170], satt[3844], sh[1984], sL[3844], sW[1280];
    __shared__ float ss1[62], ss2[62];
    __shared__ float sh2[620], soutg[620], sx11[620], st1[256], st2[32];
    const int tid = threadIdx.x;
    const int b = blockIdx.x;
    float* xcat = g_xcat + (size_t)b * 7936;

    for (int idx = tid; idx < 2170; idx += 256) {
        int n = idx / 35, f = idx - n * 35;
        sxx[idx] = (f < 30) ? g_xx1[(size_t)b * 1860 + n * 30 + f]
                            : g_xt[(size_t)b * 310 + n * 5 + (f - 30)];
    }
    for (int idx = tid; idx < 3844; idx += 256) sL[idx] = g_L[idx];
    __syncthreads();

    // GAT layer 1: 4 heads, Fin=35, Fo=32
    for (int h = 0; h < 4; ++h) {
        for (int idx = tid; idx < 1120; idx += 256) sW[idx] = ldv(gat_w, h * 1120 + idx);
        __syncthreads();
        for (int idx = tid; idx < 1984; idx += 256) {
            int n = idx / 32, o = idx - n * 32;
            float acc = 0.f;
            for (int f = 0; f < 35; ++f) acc += sxx[n * 35 + f] * sW[f * 32 + o];
            sh[idx] = acc;
        }
        __syncthreads();
        if (tid < 124) {
            int which = tid >= 62; int n = which ? tid - 62 : tid;
            float acc = 0.f;
            for (int o = 0; o < 32; ++o) {
                float v = sh[n * 32 + o]; v = v > 0.f ? v : 0.2f * v;   // leaky_relu(0.2)
                acc += v * ldv(gat_a, h * 64 + which * 32 + o);
            }
            (which ? ss2 : ss1)[n] = acc;
        }
        gat_att_L(tid, sL, ss1, ss2, satt);
        for (int idx = tid; idx < 1984; idx += 256) {
            int i = idx / 32, o = idx - i * 32;
            float acc = 0.f;
            for (int j = 0; j < 62; ++j) acc += satt[i * 62 + j] * sh[j * 32 + o];
            xcat[i * 128 + h * 32 + o] = fmaxf(acc, 0.f);
        }
        __syncthreads();
    }

    // GAT layer 2: Fin=128, Fo=10
    for (int idx = tid; idx < 1280; idx += 256) sW[idx] = ldv(out_w, idx);
    __syncthreads();
    for (int idx = tid; idx < 620; idx += 256) {
        int n = idx / 10, o = idx - n * 10;
        float acc = 0.f;
        for (int f = 0; f < 128; ++f) acc += xcat[n * 128 + f] * sW[f * 10 + o];
        sh2[idx] = acc;
    }
    __syncthreads();
    if (tid < 124) {
        int which = tid >= 62; int n = which ? tid - 62 : tid;
        float acc = 0.f;
        for (int o = 0; o < 10; ++o) {
            float v = sh2[n * 10 + o]; v = v > 0.f ? v : 0.2f * v;
            acc += v * ldv(out_a, which * 10 + o);
        }
        (which ? ss2 : ss1)[n] = acc;
    }
    gat_att_L(tid, sL, ss1, ss2, satt);
    for (int idx = tid; idx < 620; idx += 256) {
        int i = idx / 10, o = idx - i * 10;
        float acc = 0.f;
        for (int j = 0; j < 62; ++j) acc += satt[i * 62 + j] * sh2[j * 10 + o];
        soutg[idx] = fmaxf(acc, 0.f);
    }
    __syncthreads();

    if (tid < 62) {   // g1 = log_softmax(elu(outg)) -> x11 (first output)
        const float* r = soutg + tid * 10;
        float e[10]; float mx = -3.4e38f;
        for (int o = 0; o < 10; ++o) { float v = r[o]; v = v > 0.f ? v : expm1f(v); e[o] = v; mx = fmaxf(mx, v); }
        float sum = 0.f;
        for (int o = 0; o < 10; ++o) sum += expf(e[o] - mx);
        float ls = logf(sum) + mx;
        for (int o = 0; o < 10; ++o) {
            float v = e[o] - ls;
            sx11[tid * 10 + o] = v;
            stv(out, (size_t)b * 620 + tid * 10 + o, v);
        }
    }
    __syncthreads();

    {   // fc1 (620->256)
        float acc = ldv(fc1_b, tid);
        for (int f = 0; f < 620; ++f) acc += sx11[f] * ldv(fc1_w, f * 256 + tid);
        st1[tid] = acc;
    }
    __syncthreads();
    if (tid < 32) {   // fc2 (256->32)
        float acc = ldv(fc2_b, tid);
        for (int f = 0; f < 256; ++f) acc += st1[f] * ldv(fc2_w, f * 32 + tid);
        st2[tid] = acc;
    }
    __syncthreads();
    if (tid < 4) {    // fc3 (32->4) -> x4 (second output)
        float acc = ldv(fc3_b, tid);
        for (int f = 0; f < 32; ++f) acc += st2[f] * ldv(fc3_w, f * 4 + tid);
        stv(out, (size_t)B * 620 + b * 4 + tid, acc);
    }
}

extern "C" void kernel_launch(void* const* d_in, const int* in_sizes, int n_in,
                              void* d_out, int out_size, void* d_ws, size_t ws_size,
                              hipStream_t stream)
{
    const int B = in_sizes[0] / 310;   // 2048

    k_probe<<<1, 256, 0, stream>>>(d_in[0]);

    // ---- bf16 instantiation (MODE 1) ----
    {
        #define P(i) ((const bf16*)d_in[i])
        k_conv<bf16,1><<<B / 4, 256, 0, stream>>>(P(0), P(2), P(3), P(4), P(5), P(6), P(7), P(8), P(9));
        k_ln1<bf16,1><<<(B * 62 + 255) / 256, 256, 0, stream>>>(P(0), P(18), P(19), B);
        k_qkv<bf16,1><<<(B / 8) * 14, 256, 0, stream>>>(P(10), P(11), P(12), P(13), P(14), P(15));
        k_prep<bf16,1><<<1, 256, 0, stream>>>(P(1));
        #undef P
    }
    // ---- f32 instantiation (MODE 0) ----
    {
        #define P(i) ((const float*)d_in[i])
        k_conv<float,0><<<B / 4, 256, 0, stream>>>(P(0), P(2), P(3), P(4), P(5), P(6), P(7), P(8), P(9));
        k_ln1<float,0><<<(B * 62 + 255) / 256, 256, 0, stream>>>(P(0), P(18), P(19), B);
        k_qkv<float,0><<<(B / 8) * 14, 256, 0, stream>>>(P(10), P(11), P(12), P(13), P(14), P(15));
        k_prep<float,0><<<1, 256, 0, stream>>>(P(1));
        #undef P
    }

    k_attn<<<B, 256, 0, stream>>>();

    {
        #define P(i) ((const bf16*)d_in[i])
        k_lin1ffn<bf16,1><<<B / 4, 256, 0, stream>>>(P(0), P(16), P(17), P(20), P(21), P(22), P(23), P(24), P(25));
        k_gat<bf16,1><<<B, 256, 0, stream>>>(P(26), P(27), P(28), P(29), P(30), P(31), P(32), P(33), P(34), P(35),
                                             (bf16*)d_out, B);
        #undef P
    }
    {
        #define P(i) ((const float*)d_in[i])
        k_lin1ffn<float,0><<<B / 4, 256, 0, stream>>>(P(0), P(16), P(17), P(20), P(21), P(22), P(23), P(24), P(25));
        k_gat<float,0><<<B, 256, 0, stream>>>(P(26), P(27), P(28), P(29), P(30), P(31), P(32), P(33), P(34), P(35),
                                              (float*)d_out, B);
        #undef P
    }
}

// Round 5
// 1260.530 us; speedup vs baseline: 1.5290x; 1.0022x over previous
//
#include <hip/hip_runtime.h>
#include <hip/hip_bf16.h>

typedef __hip_bfloat16 bf16;

__device__ __forceinline__ float b2f(bf16 v) { return __bfloat162float(v); }
__device__ __forceinline__ bf16  f2b(float v) { return __float2bfloat16(v); }

__device__ __forceinline__ float ldv(const bf16* p, int i)  { return b2f(p[i]); }
__device__ __forceinline__ float ldv(const float* p, int i) { return p[i]; }
__device__ __forceinline__ void  stv(bf16* p, size_t i, float v)  { p[i] = f2b(v); }
__device__ __forceinline__ void  stv(float* p, size_t i, float v) { p[i] = v; }

#define SELU_SCALE 1.0507009873554805f
#define SELU_ALPHA 1.6732632423543772f
#define INV_SQRT2  0.7071067811865475f

#define NB 2048   // batch (fixed by reference)

// dtype flag + global staging
__device__ int   g_flag;                        // 1 = bf16 tensors, 0 = f32
__device__ float g_xf  [(size_t)NB * 310];      // ln1(x)
__device__ float g_qkv [(size_t)NB * 3348];     // q(744)|k(744)|v(1860) per sample
__device__ float g_x2t [(size_t)NB * 1860];     // attention output (pre-lin1)
__device__ float g_xx1 [(size_t)NB * 1860];     // conv-branch output
__device__ float g_xt  [(size_t)NB * 310];      // transformer output
__device__ float g_xcat[(size_t)NB * 7936];     // GAT1 concat [62,128]
__device__ float g_L   [3844];                  // normalized Laplacian

// transposed (contraction-contiguous) f32 weights; row strides padded to 16B
__device__ float g_qkvT [(size_t)3348 * 312];   // [o][f] f<310 valid
__device__ float g_lin1T[(size_t)310 * 1860];   // [o][f]
__device__ float g_ffn1T[(size_t)186 * 312];    // [j][f] f<310 valid
__device__ float g_ffn2T[(size_t)310 * 188];    // [o][j] j<186 valid
__device__ float g_fc1T [(size_t)256 * 620];    // [o][f]

// ---- dtype probe ----
__global__ void k_probe(const void* x0)
{
    __shared__ int cnt;
    if (threadIdx.x == 0) cnt = 0;
    __syncthreads();
    const bf16* p = (const bf16*)x0;
    int bad = 0;
    for (int i = threadIdx.x; i < 4096; i += 256) {
        float v = b2f(p[i]);
        if (!(fabsf(v) < 1e6f)) bad++;
    }
    atomicAdd(&cnt, bad);
    __syncthreads();
    if (threadIdx.x == 0) g_flag = (cnt < 32) ? 1 : 0;
}

// ---- one-time weight transposes into f32 arrays ----
#define QKVT_SZ  (3348 * 312)
#define LIN1T_SZ (310 * 1860)
#define FFN1T_SZ (186 * 312)
#define FFN2T_SZ (310 * 188)
#define FC1T_SZ  (256 * 620)
#define WPREP_TOTAL (QKVT_SZ + LIN1T_SZ + FFN1T_SZ + FFN2T_SZ + FC1T_SZ)

template<typename T, int MODE>
__global__ __launch_bounds__(256) void k_wprep(
    const T* __restrict__ qw, const T* __restrict__ kw, const T* __restrict__ vw,
    const T* __restrict__ lin1_w, const T* __restrict__ ffn_w1, const T* __restrict__ ffn_w2,
    const T* __restrict__ fc1_w)
{
    if (g_flag != MODE) return;
    int idx = blockIdx.x * 256 + threadIdx.x;
    if (idx >= WPREP_TOTAL) return;
    if (idx < QKVT_SZ) {
        int o = idx / 312, f = idx - o * 312;
        float v = 0.f;
        if (f < 310) {
            if (o < 744)       { int h = o / 124, c = o - h * 124; v = ldv(qw, h * 38440 + f * 124 + c); }
            else if (o < 1488) { int r = o - 744;  int h = r / 124, c = r - h * 124; v = ldv(kw, h * 38440 + f * 124 + c); }
            else               { int r = o - 1488; int h = r / 310, c = r - h * 310; v = ldv(vw, h * 96100 + f * 310 + c); }
        }
        g_qkvT[idx] = v;
        return;
    }
    idx -= QKVT_SZ;
    if (idx < LIN1T_SZ) {
        int o = idx / 1860, f = idx - o * 1860;
        g_lin1T[idx] = ldv(lin1_w, f * 310 + o);
        return;
    }
    idx -= LIN1T_SZ;
    if (idx < FFN1T_SZ) {
        int j = idx / 312, f = idx - j * 312;
        g_ffn1T[idx] = (f < 310) ? ldv(ffn_w1, f * 186 + j) : 0.f;
        return;
    }
    idx -= FFN1T_SZ;
    if (idx < FFN2T_SZ) {
        int o = idx / 188, j = idx - o * 188;
        g_ffn2T[idx] = (j < 186) ? ldv(ffn_w2, j * 310 + o) : 0.f;
        return;
    }
    idx -= FFN2T_SZ;
    {
        int o = idx / 620, f = idx - o * 620;
        g_fc1T[idx] = ldv(fc1_w, f * 256 + o);
    }
}

// ================= conv branch, G=4 samples/block (unchanged from R4) =================
template<typename T>
__device__ void conv_bn_selu_g(int tid, const float* sIn, int Lin, int K, int Lout,
                               const T* __restrict__ W, const T* __restrict__ cb,
                               const T* __restrict__ bng, const T* __restrict__ bnb,
                               float* sOut, int ostride, int ooff)
{
    const float bninv = rsqrtf(1.0f + 1e-5f);
    for (int idx = tid; idx < 62 * Lout; idx += 256) {
        int o = idx / Lout, l = idx - o * Lout;
        const T* wr = W + o * 62 * K;
        float a0 = 0.f, a1 = 0.f, a2 = 0.f, a3 = 0.f;
        for (int i = 0; i < 62; ++i)
            for (int k = 0; k < K; ++k) {
                float w = ldv(wr, i * K + k);
                const float4 xv = *(const float4*)(sIn + (i * Lin + l + k) * 4);
                a0 += w * xv.x; a1 += w * xv.y; a2 += w * xv.z; a3 += w * xv.w;
            }
        float bias = ldv(cb, o), gg = ldv(bng, o) * bninv, bb = ldv(bnb, o);
        float acc[4] = {a0, a1, a2, a3};
        for (int g = 0; g < 4; ++g) {
            float v = (acc[g] + bias) * gg + bb;
            sOut[(o * ostride + ooff + l) * 4 + g] =
                (v > 0.f) ? SELU_SCALE * v : SELU_SCALE * SELU_ALPHA * expm1f(v);
        }
    }
    __syncthreads();
}

template<typename T>
__device__ void chan_att_g(int tid, float* sIn, int Ls,
                           const T* __restrict__ w1, const T* __restrict__ w2,
                           float* pool, float* hid)
{
    __syncthreads();
    for (int idx = tid; idx < 496; idx += 256) {
        int which = idx >= 248; int r = idx - which * 248;
        int n = r >> 2, g = r & 3;
        float a = 0.f, m = -3.4e38f;
        for (int l = 0; l < Ls; ++l) { float v = sIn[(n * Ls + l) * 4 + g]; a += v; m = fmaxf(m, v); }
        pool[(which * 62 + n) * 4 + g] = which ? m : a / (float)Ls;
    }
    __syncthreads();
    if (tid < 120) {
        int g = tid & 3; int t = tid >> 2;
        int which = t / 15, j = t - which * 15;
        float acc = 0.f;
        for (int n = 0; n < 62; ++n) acc += pool[(which * 62 + n) * 4 + g] * ldv(w1, j * 62 + n);
        hid[(which * 16 + j) * 4 + g] = fmaxf(acc, 0.f);
    }
    __syncthreads();
    if (tid < 248) {
        int g = tid & 3, n = tid >> 2;
        float acc = 0.f;
        for (int j = 0; j < 15; ++j) acc += (hid[j * 4 + g] + hid[(16 + j) * 4 + g]) * ldv(w2, n * 15 + j);
        float s = 1.f / (1.f + expf(-acc));
        for (int l = 0; l < Ls; ++l) sIn[(n * Ls + l) * 4 + g] *= s;
    }
    __syncthreads();
}

template<typename T, int MODE>
__global__ __launch_bounds__(256) void k_conv(
    const T* __restrict__ x,
    const T* __restrict__ cw3, const T* __restrict__ cb3,
    const T* __restrict__ cw5, const T* __restrict__ cb5,
    const T* __restrict__ bn_g, const T* __restrict__ bn_b,
    const T* __restrict__ ca_w1, const T* __restrict__ ca_w2)
{
    if (g_flag != MODE) return;
    __shared__ __align__(16) float sX[310 * 4];
    __shared__ __align__(16) float sx2[496 * 4];
    __shared__ __align__(16) float sbuf[868 * 4];
    __shared__ __align__(16) float sxx1[1860 * 4];
    __shared__ float spool[124 * 4], shid[32 * 4];
    const int tid = threadIdx.x;
    const int grp = blockIdx.x;

    for (int idx = tid; idx < 310 * 4; idx += 256) {
        int o = idx >> 2, g = idx & 3;
        sX[idx] = ldv(x, (grp * 4 + g) * 310 + o);
    }
    __syncthreads();

    conv_bn_selu_g(tid, sX, 5, 3, 3, cw3, cb3, bn_g, bn_b, sx2, 8, 0);
    for (int idx = tid; idx < 310 * 4; idx += 256) {
        int p = idx >> 2, g = idx & 3; int n = p / 5, c = p - n * 5;
        sx2[(n * 8 + 3 + c) * 4 + g] = sX[idx];
    }
    chan_att_g(tid, sx2, 8, ca_w1, ca_w2, spool, shid);

    conv_bn_selu_g(tid, sx2, 8, 3, 6, cw3 + 11532, cb3 + 62, bn_g + 62, bn_b + 62, sbuf, 14, 8);
    for (int idx = tid; idx < 496 * 4; idx += 256) {
        int p = idx >> 2, g = idx & 3; int n = p >> 3, c = p & 7;
        sbuf[(n * 14 + c) * 4 + g] = sx2[idx];
    }
    __syncthreads();
    conv_bn_selu_g(tid, sbuf, 14, 3, 12, cw3 + 2 * 11532, cb3 + 124, bn_g + 124, bn_b + 124, sxx1, 30, 0);

    conv_bn_selu_g(tid, sx2, 8, 5, 4, cw5, cb5, bn_g + 186, bn_b + 186, sbuf, 12, 0);
    for (int idx = tid; idx < 496 * 4; idx += 256) {
        int p = idx >> 2, g = idx & 3; int n = p >> 3, c = p & 7;
        sbuf[(n * 12 + 4 + c) * 4 + g] = sx2[idx];
    }
    __syncthreads();
    conv_bn_selu_g(tid, sbuf, 12, 5, 8, cw5 + 19220, cb5 + 62, bn_g + 248, bn_b + 248, sxx1, 30, 12);

    conv_bn_selu_g(tid, sx2, 8, 3, 6, cw3 + 3 * 11532, cb3 + 186, bn_g + 310, bn_b + 310, sbuf, 14, 0);
    for (int idx = tid; idx < 496 * 4; idx += 256) {
        int p = idx >> 2, g = idx & 3; int n = p >> 3, c = p & 7;
        sbuf[(n * 14 + 6 + c) * 4 + g] = sx2[idx];
    }
    __syncthreads();
    conv_bn_selu_g(tid, sbuf, 14, 5, 10, cw5 + 2 * 19220, cb5 + 124, bn_g + 372, bn_b + 372, sxx1, 30, 20);

    chan_att_g(tid, sxx1, 30, ca_w1 + 930, ca_w2 + 930, spool, shid);

    for (int idx = tid; idx < 1860 * 4; idx += 256) {
        int p = idx >> 2, g = idx & 3;
        g_xx1[(size_t)(grp * 4 + g) * 1860 + p] = sxx1[idx];
    }
}

// ================= transformer =================
template<typename T, int MODE>
__global__ __launch_bounds__(256) void k_ln1(
    const T* __restrict__ x, const T* __restrict__ ln1_g, const T* __restrict__ ln1_b, int B)
{
    if (g_flag != MODE) return;
    int r = blockIdx.x * 256 + threadIdx.x;
    if (r >= B * 62) return;
    int b = r / 62, i = r - b * 62;
    float xv[5], m = 0.f, s = 0.f;
    for (int c = 0; c < 5; ++c) { xv[c] = ldv(x, b * 310 + i * 5 + c); m += xv[c]; s += xv[c] * xv[c]; }
    m *= 0.2f;
    float inv = rsqrtf(fmaxf(s * 0.2f - m * m, 0.f) + 1e-5f);
    for (int c = 0; c < 5; ++c)
        g_xf[(size_t)b * 310 + i * 5 + c] = (xv[c] - m) * inv * ldv(ln1_g, c) + ldv(ln1_b, c);
}

// QKV GEMM: 8 samples/block, transposed f32 weights, float4 over f.
template<typename T, int MODE>
__global__ __launch_bounds__(256) void k_qkv(
    const T* __restrict__ qb, const T* __restrict__ kb, const T* __restrict__ vb)
{
    if (g_flag != MODE) return;
    __shared__ __align__(16) float sxf[310 * 8];
    const int tid = threadIdx.x;
    const int grp = blockIdx.x / 14;
    const int tile = blockIdx.x - grp * 14;

    for (int idx = tid; idx < 310 * 8; idx += 256) {
        int f = idx >> 3, g = idx & 7;
        sxf[idx] = g_xf[(size_t)(grp * 8 + g) * 310 + f];
    }
    __syncthreads();

    int o = tile * 256 + tid;
    if (o >= 3348) return;

    float bias;
    if (o < 744)       bias = ldv(qb, o);
    else if (o < 1488) bias = ldv(kb, o - 744);
    else               bias = ldv(vb, o - 1488);

    const float* W = g_qkvT + (size_t)o * 312;
    float a0 = bias, a1 = bias, a2 = bias, a3 = bias, a4 = bias, a5 = bias, a6 = bias, a7 = bias;
#define QSTEP(wk, ff) { const float4 p = *(const float4*)(sxf + (ff) * 8); \
                        const float4 qq = *(const float4*)(sxf + (ff) * 8 + 4); \
                        a0 += (wk) * p.x; a1 += (wk) * p.y; a2 += (wk) * p.z; a3 += (wk) * p.w; \
                        a4 += (wk) * qq.x; a5 += (wk) * qq.y; a6 += (wk) * qq.z; a7 += (wk) * qq.w; }
    for (int f = 0; f < 308; f += 4) {
        const float4 w = *(const float4*)(W + f);
        QSTEP(w.x, f) QSTEP(w.y, f + 1) QSTEP(w.z, f + 2) QSTEP(w.w, f + 3)
    }
    QSTEP(W[308], 308) QSTEP(W[309], 309)
#undef QSTEP
    float acc[8] = {a0, a1, a2, a3, a4, a5, a6, a7};
    for (int g = 0; g < 8; ++g) g_qkv[(size_t)(grp * 8 + g) * 3348 + o] = acc[g];
}

// per-sample attention -> g_x2t
__global__ __launch_bounds__(256) void k_attn()
{
    __shared__ float sqkv[3348];
    __shared__ float satt[3844];
    const int tid = threadIdx.x;
    const int b = blockIdx.x;

    for (int i = tid; i < 3348; i += 256) sqkv[i] = g_qkv[(size_t)b * 3348 + i];
    __syncthreads();

    for (int h = 0; h < 6; ++h) {
        const float* q = sqkv + h * 124;
        const float* k = sqkv + 744 + h * 124;
        const float* v = sqkv + 1488 + h * 310;
        for (int idx = tid; idx < 3844; idx += 256) {
            int i = idx / 62, j = idx - i * 62;
            satt[idx] = (q[i * 2] * k[j * 2] + q[i * 2 + 1] * k[j * 2 + 1]) * INV_SQRT2;
        }
        __syncthreads();
        if (tid < 62) {
            float* row = satt + tid * 62;
            float mx = -3.4e38f;
            for (int j = 0; j < 62; ++j) mx = fmaxf(mx, row[j]);
            float sum = 0.f;
            for (int j = 0; j < 62; ++j) { float e = expf(row[j] - mx); row[j] = e; sum += e; }
            float inv = 1.f / sum;
            for (int j = 0; j < 62; ++j) row[j] *= inv;
        }
        __syncthreads();
        for (int idx = tid; idx < 310; idx += 256) {
            int i = idx / 5, c = idx - i * 5;
            float acc = 0.f;
            for (int j = 0; j < 62; ++j) acc += satt[j * 62 + i] * v[j * 5 + c];
            g_x2t[(size_t)b * 1860 + i * 30 + h * 5 + c] = acc;
        }
        __syncthreads();
    }
}

// lin1 + residual + LN2 + FFN + residual: 4 samples/block, transposed weights
template<typename T, int MODE>
__global__ __launch_bounds__(256) void k_lin1ffn(
    const T* __restrict__ x, const T* __restrict__ lin1_b,
    const T* __restrict__ ln2_g, const T* __restrict__ ln2_b,
    const T* __restrict__ ffn_b1, const T* __restrict__ ffn_b2)
{
    if (g_flag != MODE) return;
    __shared__ __align__(16) float sx2t[1860 * 4];
    __shared__ __align__(16) float sX[310 * 4];
    __shared__ __align__(16) float sx21[310 * 4];
    __shared__ __align__(16) float sxf[310 * 4];
    __shared__ __align__(16) float shg[186 * 4];
    __shared__ __align__(16) float spart[620 * 4];
    const int tid = threadIdx.x;
    const int grp = blockIdx.x;

    for (int idx = tid; idx < 1860 * 4; idx += 256) {
        int f = idx >> 2, g = idx & 3;
        sx2t[idx] = g_x2t[(size_t)(grp * 4 + g) * 1860 + f];
    }
    for (int idx = tid; idx < 310 * 4; idx += 256) {
        int o = idx >> 2, g = idx & 3;
        sX[idx] = ldv(x, (grp * 4 + g) * 310 + o);
    }
    __syncthreads();

#define XSTEP(wk, ff, Xb) { const float4 xv = *(const float4*)((Xb) + (ff) * 4); \
                            a0 += (wk) * xv.x; a1 += (wk) * xv.y; a2 += (wk) * xv.z; a3 += (wk) * xv.w; }
    // lin1 partials: halves [0,928) and [928,1860) (both 16B-aligned, %4==0)
    for (int item = tid; item < 620; item += 256) {
        int half = item >= 310; int o = item - half * 310;
        int fbase = half ? 928 : 0;
        int fcnt = half ? 932 : 928;
        const float* W = g_lin1T + (size_t)o * 1860 + fbase;
        const float* Xb = sx2t + fbase * 4;
        float a0 = 0.f, a1 = 0.f, a2 = 0.f, a3 = 0.f;
        for (int f = 0; f < fcnt; f += 4) {
            const float4 w = *(const float4*)(W + f);
            XSTEP(w.x, f, Xb) XSTEP(w.y, f + 1, Xb) XSTEP(w.z, f + 2, Xb) XSTEP(w.w, f + 3, Xb)
        }
        spart[item * 4 + 0] = a0; spart[item * 4 + 1] = a1;
        spart[item * 4 + 2] = a2; spart[item * 4 + 3] = a3;
    }
    __syncthreads();
    for (int o = tid; o < 310; o += 256) {
        float bias = ldv(lin1_b, o);
        for (int g = 0; g < 4; ++g)
            sx21[o * 4 + g] = spart[o * 4 + g] + spart[(310 + o) * 4 + g] + bias + sX[o * 4 + g];
    }
    __syncthreads();

    // LN2
    if (tid < 248) {
        int i = tid >> 2, g = tid & 3;
        float m = 0.f, s = 0.f;
        for (int c = 0; c < 5; ++c) { float v = sx21[(i * 5 + c) * 4 + g]; m += v; s += v * v; }
        m *= 0.2f;
        float inv = rsqrtf(fmaxf(s * 0.2f - m * m, 0.f) + 1e-5f);
        for (int c = 0; c < 5; ++c)
            sxf[(i * 5 + c) * 4 + g] = (sx21[(i * 5 + c) * 4 + g] - m) * inv * ldv(ln2_g, c) + ldv(ln2_b, c);
    }
    __syncthreads();

    // FFN up + exact gelu
    if (tid < 186) {
        const float* W = g_ffn1T + (size_t)tid * 312;
        float bias = ldv(ffn_b1, tid);
        float a0 = bias, a1 = bias, a2 = bias, a3 = bias;
        for (int f = 0; f < 308; f += 4) {
            const float4 w = *(const float4*)(W + f);
            XSTEP(w.x, f, sxf) XSTEP(w.y, f + 1, sxf) XSTEP(w.z, f + 2, sxf) XSTEP(w.w, f + 3, sxf)
        }
        XSTEP(W[308], 308, sxf) XSTEP(W[309], 309, sxf)
        shg[tid * 4 + 0] = 0.5f * a0 * (1.f + erff(a0 * INV_SQRT2));
        shg[tid * 4 + 1] = 0.5f * a1 * (1.f + erff(a1 * INV_SQRT2));
        shg[tid * 4 + 2] = 0.5f * a2 * (1.f + erff(a2 * INV_SQRT2));
        shg[tid * 4 + 3] = 0.5f * a3 * (1.f + erff(a3 * INV_SQRT2));
    }
    __syncthreads();

    // FFN down + residual -> g_xt
    for (int o = tid; o < 310; o += 256) {
        const float* W = g_ffn2T + (size_t)o * 188;
        float bias = ldv(ffn_b2, o);
        float a0 = bias, a1 = bias, a2 = bias, a3 = bias;
        for (int j = 0; j < 184; j += 4) {
            const float4 w = *(const float4*)(W + j);
            XSTEP(w.x, j, shg) XSTEP(w.y, j + 1, shg) XSTEP(w.z, j + 2, shg) XSTEP(w.w, j + 3, shg)
        }
        XSTEP(W[184], 184, shg) XSTEP(W[185], 185, shg)
        g_xt[(size_t)(grp * 4 + 0) * 310 + o] = a0 + sx21[o * 4 + 0];
        g_xt[(size_t)(grp * 4 + 1) * 310 + o] = a1 + sx21[o * 4 + 1];
        g_xt[(size_t)(grp * 4 + 2) * 310 + o] = a2 + sx21[o * 4 + 2];
        g_xt[(size_t)(grp * 4 + 3) * 310 + o] = a3 + sx21[o * 4 + 3];
    }
#undef XSTEP
}

// ================= GAT =================
template<typename T, int MODE>
__global__ __launch_bounds__(256) void k_prep(const T* __restrict__ A)
{
    if (g_flag != MODE) return;
    __shared__ float sdinv[62];
    const int tid = threadIdx.x;
    if (tid < 62) {
        float s = 0.f;
        for (int m = 0; m < 62; ++m) s += fmaxf(ldv(A, tid * 62 + m), 0.f);
        sdinv[tid] = rsqrtf(s + 1e-10f);
    }
    __syncthreads();
    for (int idx = tid; idx < 3844; idx += 256) {
        int n = idx / 62, m = idx - n * 62;
        g_L[idx] = sdinv[n] * fmaxf(ldv(A, idx), 0.f) * sdinv[m];
    }
}

template<typename T, int MODE>
__global__ __launch_bounds__(256) void k_gat(
    const T* __restrict__ gat_w, const T* __restrict__ gat_a,
    const T* __restrict__ out_w, const T* __restrict__ out_a,
    const T* __restrict__ fc1_b,
    const T* __restrict__ fc2_w, const T* __restrict__ fc2_b,
    const T* __restrict__ fc3_w, const T* __restrict__ fc3_b,
    T* __restrict__ out, int B)
{
    if (g_flag != MODE) return;
    __shared__ __align__(16) float sxx[2170];    // [62][35]
    __shared__ __align__(16) float satt[3844];
    __shared__ __align__(16) float sh[1984];     // [62][32]
    __shared__ __align__(16) float sW[1280];
    __shared__ float ss1[62], ss2[62];
    __shared__ __align__(16) float sh2[620], soutg[620], sx11[620];
    __shared__ __align__(16) float st1[256], st2[32];
    const int tid = threadIdx.x;
    const int b = blockIdx.x;
    float* xcat = g_xcat + (size_t)b * 7936;

    for (int idx = tid; idx < 2170; idx += 256) {
        int n = idx / 35, f = idx - n * 35;
        sxx[idx] = (f < 30) ? g_xx1[(size_t)b * 1860 + n * 30 + f]
                            : g_xt[(size_t)b * 310 + n * 5 + (f - 30)];
    }
    __syncthreads();

    // GAT layer 1: 4 heads, Fin=35, Fo=32
    for (int h = 0; h < 4; ++h) {
        for (int idx = tid; idx < 1120; idx += 256) sW[idx] = ldv(gat_w, h * 1120 + idx);
        __syncthreads();
        // h = xx @ W  (thread = (n, o-quad), float4 over o)
        for (int item = tid; item < 496; item += 256) {
            int n = item >> 3, oq = (item & 7) * 4;
            float a0 = 0.f, a1 = 0.f, a2 = 0.f, a3 = 0.f;
            const float* xr = sxx + n * 35;
            for (int f = 0; f < 35; ++f) {
                float xv = xr[f];
                const float4 w = *(const float4*)(sW + f * 32 + oq);
                a0 += xv * w.x; a1 += xv * w.y; a2 += xv * w.z; a3 += xv * w.w;
            }
            float* hp = sh + n * 32 + oq;
            hp[0] = a0; hp[1] = a1; hp[2] = a2; hp[3] = a3;
        }
        __syncthreads();
        // s1/s2
        if (tid < 124) {
            int which = tid >= 62; int n = which ? tid - 62 : tid;
            float acc = 0.f;
            for (int o = 0; o < 32; ++o) {
                float v = sh[n * 32 + o]; v = v > 0.f ? v : 0.2f * v;
                acc += v * ldv(gat_a, h * 64 + which * 32 + o);
            }
            (which ? ss2 : ss1)[n] = acc;
        }
        __syncthreads();
        // scores (parallel over all entries; g_L from L2)
        for (int idx = tid; idx < 3844; idx += 256) {
            int n = idx / 62, m = idx - n * 62;
            float dj = 0.8f * g_L[idx] + 0.2f * (ss1[n] + ss2[m]);
            satt[idx] = dj > 0.f ? dj : -1e12f;
        }
        __syncthreads();
        // column softmax (over n, per column m)
        if (tid < 62) {
            int m = tid;
            float mx = -3.4e38f;
            for (int n = 0; n < 62; ++n) mx = fmaxf(mx, satt[n * 62 + m]);
            float sum = 0.f;
            for (int n = 0; n < 62; ++n) { float e = expf(satt[n * 62 + m] - mx); satt[n * 62 + m] = e; sum += e; }
            float inv = 1.f / sum;
            for (int n = 0; n < 62; ++n) satt[n * 62 + m] *= inv;
        }
        __syncthreads();
        // apply: out[i,o] = relu(sum_j att[i,j] h[j,o]) -> xcat (float4 over o)
        for (int item = tid; item < 496; item += 256) {
            int i = item >> 3, oq = (item & 7) * 4;
            float a0 = 0.f, a1 = 0.f, a2 = 0.f, a3 = 0.f;
            const float* ar = satt + i * 62;
            for (int j = 0; j < 62; ++j) {
                float av = ar[j];
                const float4 hv = *(const float4*)(sh + j * 32 + oq);
                a0 += av * hv.x; a1 += av * hv.y; a2 += av * hv.z; a3 += av * hv.w;
            }
            float4 r;
            r.x = fmaxf(a0, 0.f); r.y = fmaxf(a1, 0.f); r.z = fmaxf(a2, 0.f); r.w = fmaxf(a3, 0.f);
            *(float4*)(xcat + i * 128 + h * 32 + oq) = r;
        }
        __syncthreads();
    }

    // GAT layer 2: Fin=128, Fo=10
    for (int idx = tid; idx < 1280; idx += 256) sW[idx] = ldv(out_w, idx);
    __syncthreads();
    for (int idx = tid; idx < 620; idx += 256) {
        int n = idx / 10, o = idx - n * 10;
        const float* xc = xcat + n * 128;
        float acc = 0.f;
        for (int f = 0; f < 128; f += 4) {
            const float4 xv = *(const float4*)(xc + f);
            acc += xv.x * sW[(f + 0) * 10 + o] + xv.y * sW[(f + 1) * 10 + o]
                 + xv.z * sW[(f + 2) * 10 + o] + xv.w * sW[(f + 3) * 10 + o];
        }
        sh2[idx] = acc;
    }
    __syncthreads();
    if (tid < 124) {
        int which = tid >= 62; int n = which ? tid - 62 : tid;
        float acc = 0.f;
        for (int o = 0; o < 10; ++o) {
            float v = sh2[n * 10 + o]; v = v > 0.f ? v : 0.2f * v;
            acc += v * ldv(out_a, which * 10 + o);
        }
        (which ? ss2 : ss1)[n] = acc;
    }
    __syncthreads();
    for (int idx = tid; idx < 3844; idx += 256) {
        int n = idx / 62, m = idx - n * 62;
        float dj = 0.8f * g_L[idx] + 0.2f * (ss1[n] + ss2[m]);
        satt[idx] = dj > 0.f ? dj : -1e12f;
    }
    __syncthreads();
    if (tid < 62) {
        int m = tid;
        float mx = -3.4e38f;
        for (int n = 0; n < 62; ++n) mx = fmaxf(mx, satt[n * 62 + m]);
        float sum = 0.f;
        for (int n = 0; n < 62; ++n) { float e = expf(satt[n * 62 + m] - mx); satt[n * 62 + m] = e; sum += e; }
        float inv = 1.f / sum;
        for (int n = 0; n < 62; ++n) satt[n * 62 + m] *= inv;
    }
    __syncthreads();
    for (int idx = tid; idx < 620; idx += 256) {
        int i = idx / 10, o = idx - i * 10;
        const float* ar = satt + i * 62;
        float acc = 0.f;
        for (int j = 0; j < 62; ++j) acc += ar[j] * sh2[j * 10 + o];
        soutg[idx] = fmaxf(acc, 0.f);
    }
    __syncthreads();

    if (tid < 62) {   // g1 = log_softmax(elu(outg)) -> x11
        const float* r = soutg + tid * 10;
        float e[10]; float mx = -3.4e38f;
        for (int o = 0; o < 10; ++o) { float v = r[o]; v = v > 0.f ? v : expm1f(v); e[o] = v; mx = fmaxf(mx, v); }
        float sum = 0.f;
        for (int o = 0; o < 10; ++o) sum += expf(e[o] - mx);
        float ls = logf(sum) + mx;
        for (int o = 0; o < 10; ++o) {
            float v = e[o] - ls;
            sx11[tid * 10 + o] = v;
            stv(out, (size_t)b * 620 + tid * 10 + o, v);
        }
    }
    __syncthreads();

    {   // fc1 (620->256), transposed weights + float4
        const float* W = g_fc1T + (size_t)tid * 620;
        float acc = ldv(fc1_b, tid);
        for (int f = 0; f < 620; f += 4) {
            const float4 w = *(const float4*)(W + f);
            const float4 xv = *(const float4*)(sx11 + f);
            acc += w.x * xv.x + w.y * xv.y + w.z * xv.z + w.w * xv.w;
        }
        st1[tid] = acc;
    }
    __syncthreads();
    if (tid < 32) {
        float acc = ldv(fc2_b, tid);
        for (int f = 0; f < 256; ++f) acc += st1[f] * ldv(fc2_w, f * 32 + tid);
        st2[tid] = acc;
    }
    __syncthreads();
    if (tid < 4) {
        float acc = ldv(fc3_b, tid);
        for (int f = 0; f < 32; ++f) acc += st2[f] * ldv(fc3_w, f * 4 + tid);
        stv(out, (size_t)B * 620 + b * 4 + tid, acc);
    }
}

extern "C" void kernel_launch(void* const* d_in, const int* in_sizes, int n_in,
                              void* d_out, int out_size, void* d_ws, size_t ws_size,
                              hipStream_t stream)
{
    const int B = in_sizes[0] / 310;   // 2048
    const int wprep_blocks = (WPREP_TOTAL + 255) / 256;

    k_probe<<<1, 256, 0, stream>>>(d_in[0]);

    // ---- bf16 instantiation (MODE 1) ----
    {
        #define P(i) ((const bf16*)d_in[i])
        k_wprep<bf16,1><<<wprep_blocks, 256, 0, stream>>>(P(10), P(12), P(14), P(16), P(22), P(24), P(30));
        k_conv<bf16,1><<<B / 4, 256, 0, stream>>>(P(0), P(2), P(3), P(4), P(5), P(6), P(7), P(8), P(9));
        k_ln1<bf16,1><<<(B * 62 + 255) / 256, 256, 0, stream>>>(P(0), P(18), P(19), B);
        k_qkv<bf16,1><<<(B / 8) * 14, 256, 0, stream>>>(P(11), P(13), P(15));
        k_prep<bf16,1><<<1, 256, 0, stream>>>(P(1));
        #undef P
    }
    // ---- f32 instantiation (MODE 0) ----
    {
        #define P(i) ((const float*)d_in[i])
        k_wprep<float,0><<<wprep_blocks, 256, 0, stream>>>(P(10), P(12), P(14), P(16), P(22), P(24), P(30));
        k_conv<float,0><<<B / 4, 256, 0, stream>>>(P(0), P(2), P(3), P(4), P(5), P(6), P(7), P(8), P(9));
        k_ln1<float,0><<<(B * 62 + 255) / 256, 256, 0, stream>>>(P(0), P(18), P(19), B);
        k_qkv<float,0><<<(B / 8) * 14, 256, 0, stream>>>(P(11), P(13), P(15));
        k_prep<float,0><<<1, 256, 0, stream>>>(P(1));
        #undef P
    }

    k_attn<<<B, 256, 0, stream>>>();

    {
        #define P(i) ((const bf16*)d_in[i])
        k_lin1ffn<bf16,1><<<B / 4, 256, 0, stream>>>(P(0), P(17), P(20), P(21), P(23), P(25));
        k_gat<bf16,1><<<B, 256, 0, stream>>>(P(26), P(27), P(28), P(29), P(31), P(32), P(33), P(34), P(35),
                                             (bf16*)d_out, B);
        #undef P
    }
    {
        #define P(i) ((const float*)d_in[i])
        k_lin1ffn<float,0><<<B / 4, 256, 0, stream>>>(P(0), P(17), P(20), P(21), P(23), P(25));
        k_gat<float,0><<<B, 256, 0, stream>>>(P(26), P(27), P(28), P(29), P(31), P(32), P(33), P(34), P(35),
                                              (float*)d_out, B);
        #undef P
    }
}